// Round 7
// baseline (242.140 us; speedup 1.0000x reference)
//
#include <hip/hip_runtime.h>
#include <hip/hip_bf16.h>

// Problem constants (reference: B=2, T=2048, C=2048, NH=16, NKV=4, HD=128, GATE_CH=12)
#define BB   2
#define TT   2048
#define CC   2048
#define NHq  16
#define NKVq 4
#define HDq  128
#define ROWS (BB*TT)          // 4096
#define NQKV (NHq*HDq + 2*NKVq*HDq)  // 3072

using bf16 = __hip_bfloat16;
using short8  = __attribute__((ext_vector_type(8))) short;
using short4v = __attribute__((ext_vector_type(4))) short;
using f32x4   = __attribute__((ext_vector_type(4))) float;

#define MFMA16(a,b,c) __builtin_amdgcn_mfma_f32_16x16x32_bf16((a),(b),(c),0,0,0)

// async global->LDS, 16B per lane. LDS dest must be wave-uniform-base + lane*16.
__device__ __forceinline__ void gll16(const bf16* g, void* l) {
    __builtin_amdgcn_global_load_lds((const __attribute__((address_space(1))) void*)g,
                                     (__attribute__((address_space(3))) void*)l,
                                     16, 0, 0);
}

// ---------------- fused cast: all fp32 inputs -> contiguous bf16 ws regions ----------------
// dst layout: [xb 8388608 | wq 4194304 | wk 1048576 | wv 1048576 | wproj 4194304]
// Wq/Wk rows are chunk-swapped (32-chunks 1<->2 within each 128-row head) so the
// fused RoPE epilogue in gemm_qkv has both rotation partners register-local.
__global__ void cast_all(const float* __restrict__ x,  const float* __restrict__ wq,
                         const float* __restrict__ wk, const float* __restrict__ wv,
                         const float* __restrict__ wp, bf16* __restrict__ dst) {
    long e = ((long)blockIdx.x * 256 + threadIdx.x) * 4;
    const float* src; long off; long dsto = e; int permute = 0; long rbase = 0;
    if (e < 8388608L)       { src = x;  off = e; }
    else if (e < 12582912L) { src = wq; off = e - 8388608L;  permute = 1; rbase = 8388608L; }
    else if (e < 13631488L) { src = wk; off = e - 12582912L; permute = 1; rbase = 12582912L; }
    else if (e < 14680064L) { src = wv; off = e - 13631488L; }
    else                    { src = wp; off = e - 14680064L; }
    if (permute) {
        long row = off >> 11, col = off & 2047;
        int hl = (int)(row & 127), c = hl >> 5;
        int hl2 = (c == 1) ? hl + 32 : (c == 2) ? hl - 32 : hl;
        dsto = rbase + ((row & ~127L) | hl2) * 2048 + col;
    }
    float4 v = *reinterpret_cast<const float4*>(src + off);
    ushort4 o;
    o.x = __bfloat16_as_ushort(__float2bfloat16(v.x));
    o.y = __bfloat16_as_ushort(__float2bfloat16(v.y));
    o.z = __bfloat16_as_ushort(__float2bfloat16(v.z));
    o.w = __bfloat16_as_ushort(__float2bfloat16(v.w));
    *reinterpret_cast<ushort4*>(dst + dsto) = o;
}

// ---------------- bf16 MFMA GEMM (m97 + XCD swizzle), used for out-proj ----------------
template<int OUT_F32>
__global__ __launch_bounds__(256) void gemm_bt(const bf16* __restrict__ A,
                                               const bf16* __restrict__ B,
                                               void* __restrict__ Cp,
                                               int M, int N, int K) {
    const int nwg  = gridDim.x * gridDim.y;
    const int flat = blockIdx.y * gridDim.x + blockIdx.x;
    const int flat2 = (flat & 7) * (nwg >> 3) + (flat >> 3);   // XCD-chunked, bijective
    const int bm = (flat2 % gridDim.x) * 128;
    const int bn = (flat2 / gridDim.x) * 128;
    const int tid = threadIdx.x;
    const int lane = tid & 63;
    const int w = tid >> 6;
    const int wr = w >> 1, wc = w & 1;   // 2x2 waves of 64x64

    __shared__ __align__(16) bf16 As[128 * 32];
    __shared__ __align__(16) bf16 Bs[128 * 32];

    f32x4 acc[4][4];
#pragma unroll
    for (int i = 0; i < 4; ++i)
#pragma unroll
        for (int j = 0; j < 4; ++j) acc[i][j] = f32x4{0.f, 0.f, 0.f, 0.f};

    const int srow = tid >> 2;
    const int scol = (tid & 3) * 8;

    for (int k0 = 0; k0 < K; k0 += 32) {
        __syncthreads();
#pragma unroll
        for (int p = 0; p < 2; ++p) {
            gll16(&A[(size_t)(bm + p * 64 + srow) * K + k0 + scol], (char*)As + p * 4096 + tid * 16);
            gll16(&B[(size_t)(bn + p * 64 + srow) * K + k0 + scol], (char*)Bs + p * 4096 + tid * 16);
        }
        __syncthreads();

        const int fr = lane & 15;
        const int kq = (lane >> 4) * 8;
        short8 af[4], bfr[4];
#pragma unroll
        for (int m = 0; m < 4; ++m)
            af[m] = *reinterpret_cast<const short8*>(&As[(wr * 64 + m * 16 + fr) * 32 + kq]);
#pragma unroll
        for (int n = 0; n < 4; ++n)
            bfr[n] = *reinterpret_cast<const short8*>(&Bs[(wc * 64 + n * 16 + fr) * 32 + kq]);
#pragma unroll
        for (int m = 0; m < 4; ++m)
#pragma unroll
            for (int n = 0; n < 4; ++n)
                acc[m][n] = MFMA16(af[m], bfr[n], acc[m][n]);
    }

    const int cr = (lane >> 4) * 4;
    const int cc = lane & 15;
#pragma unroll
    for (int m = 0; m < 4; ++m)
#pragma unroll
        for (int n = 0; n < 4; ++n) {
            int row = bm + wr * 64 + m * 16 + cr;
            int col = bn + wc * 64 + n * 16 + cc;
#pragma unroll
            for (int j = 0; j < 4; ++j) {
                float v = acc[m][n][j];
                if (OUT_F32) ((float*)Cp)[(size_t)(row + j) * N + col] = v;
                else         ((bf16*)Cp)[(size_t)(row + j) * N + col] = __float2bfloat16(v);
            }
        }
}

// ---------------- qkv GEMM, 64x64 wave-tiles, fused postproc ----------------
// B rows chunk-swapped at cast: wave (wr,wc) holds RoPE pairs register-locally:
// d = wc*32 + p*16 + cc (p=0,1), x1=acc[m][p], x2=acc[m][p+2]. RMSNorm partials
// exchanged between wc-paired waves via 1KB LDS. v blocks: gate+ve add.
__global__ __launch_bounds__(256) void gemm_qkv(const bf16* __restrict__ A,
                                                const bf16* __restrict__ B,
                                                bf16* __restrict__ qkv,
                                                const float* __restrict__ x,
                                                const float* __restrict__ ve,
                                                const float* __restrict__ cosb,
                                                const float* __restrict__ sinb,
                                                const float* __restrict__ Wgate) {
    const int K = CC;
    const int nwg  = gridDim.x * gridDim.y;
    const int flat = blockIdx.y * gridDim.x + blockIdx.x;
    const int flat2 = (flat & 7) * (nwg >> 3) + (flat >> 3);
    const int bm = (flat2 % gridDim.x) * 128;
    const int bn = (flat2 / gridDim.x) * 128;
    const int tid = threadIdx.x;
    const int lane = tid & 63;
    const int w = tid >> 6;
    const int wr = w >> 1, wc = w & 1;

    __shared__ __align__(16) bf16 As[128 * 32];
    __shared__ __align__(16) bf16 Bs[128 * 32];
    __shared__ float exch[2][2][64];   // [wc][wr][local row] RMS partials

    f32x4 acc[4][4];
#pragma unroll
    for (int i = 0; i < 4; ++i)
#pragma unroll
        for (int j = 0; j < 4; ++j) acc[i][j] = f32x4{0.f, 0.f, 0.f, 0.f};

    const int srow = tid >> 2;
    const int scol = (tid & 3) * 8;

    for (int k0 = 0; k0 < K; k0 += 32) {
        __syncthreads();
#pragma unroll
        for (int p = 0; p < 2; ++p) {
            gll16(&A[(size_t)(bm + p * 64 + srow) * K + k0 + scol], (char*)As + p * 4096 + tid * 16);
            gll16(&B[(size_t)(bn + p * 64 + srow) * K + k0 + scol], (char*)Bs + p * 4096 + tid * 16);
        }
        __syncthreads();

        const int fr = lane & 15;
        const int kq = (lane >> 4) * 8;
        short8 af[4], bfr[4];
#pragma unroll
        for (int m = 0; m < 4; ++m)
            af[m] = *reinterpret_cast<const short8*>(&As[(wr * 64 + m * 16 + fr) * 32 + kq]);
#pragma unroll
        for (int n = 0; n < 4; ++n)
            bfr[n] = *reinterpret_cast<const short8*>(&Bs[(wc * 64 + n * 16 + fr) * 32 + kq]);
#pragma unroll
        for (int m = 0; m < 4; ++m)
#pragma unroll
            for (int n = 0; n < 4; ++n)
                acc[m][n] = MFMA16(af[m], bfr[n], acc[m][n]);
    }

    const int cc_ = lane & 15;
    const int hi  = lane >> 4;

    if (bn < 2560) {
        // ---- RoPE + RMSNorm + *1.2 ----
#pragma unroll
        for (int m = 0; m < 4; ++m)
#pragma unroll
            for (int j = 0; j < 4; ++j) {
                const int row = bm + wr * 64 + m * 16 + hi * 4 + j;
                const int t = row & (TT - 1);
                float ss = 0.f;
#pragma unroll
                for (int p = 0; p < 2; ++p) {
                    const int d = wc * 32 + p * 16 + cc_;
                    float cv = cosb[t * 64 + d], sv = sinb[t * 64 + d];
                    float x1 = acc[m][p][j], x2 = acc[m][p + 2][j];
                    float r1 =  x1 * cv + x2 * sv;
                    float r2 = -x1 * sv + x2 * cv;
                    ss += r1 * r1 + r2 * r2;
                    acc[m][p][j] = r1; acc[m][p + 2][j] = r2;
                }
#pragma unroll
                for (int mm = 1; mm < 16; mm <<= 1) ss += __shfl_xor(ss, mm);
                if (cc_ == 0) exch[wc][wr][m * 16 + hi * 4 + j] = ss;
            }
        __syncthreads();
#pragma unroll
        for (int m = 0; m < 4; ++m)
#pragma unroll
            for (int j = 0; j < 4; ++j) {
                const int row = bm + wr * 64 + m * 16 + hi * 4 + j;
                const int lr = m * 16 + hi * 4 + j;
                float sst = exch[0][wr][lr] + exch[1][wr][lr];
                float sc = rsqrtf(sst * (1.0f / 128.0f) + 1e-6f) * 1.2f;
                bf16* o = qkv + (size_t)row * NQKV + bn;
#pragma unroll
                for (int p = 0; p < 2; ++p) {
                    const int d = wc * 32 + p * 16 + cc_;
                    o[d]      = __float2bfloat16(acc[m][p][j] * sc);
                    o[d + 64] = __float2bfloat16(acc[m][p + 2][j] * sc);
                }
            }
    } else {
        // ---- v: gate + ve add ----
        const int kvh = (bn - 2560) >> 7;
#pragma unroll
        for (int m = 0; m < 4; ++m)
#pragma unroll
            for (int j = 0; j < 4; ++j) {
                const int row = bm + wr * 64 + m * 16 + hi * 4 + j;
                float g = 0.f;
#pragma unroll
                for (int c = 0; c < 12; ++c) g += x[(size_t)row * CC + c] * Wgate[kvh * 12 + c];
                g = 3.0f / (1.0f + __expf(-g));
                bf16* o = qkv + (size_t)row * NQKV + bn + wc * 64;
                const float* vep = ve + (size_t)row * 512 + kvh * 128 + wc * 64;
#pragma unroll
                for (int n = 0; n < 4; ++n) {
                    const int d = n * 16 + cc_;
                    o[d] = __float2bfloat16(acc[m][n][j] + g * vep[d]);
                }
            }
    }
}

// ---------------- MFMA flash attention v5 ----------------
// R4 structure (K dbuf via gll16, V reg-prefetch) + key-slot permutation
// (slot = 4*fr + n, applied to BOTH Ps and Vt) so P writes are one ds_write_b64,
// + linear [64]-stride Ps/Vt with ^((row&7)<<4) byte XOR (16B-aligned, uniform banks).
__global__ __launch_bounds__(256, 2) void attn_mfma(const bf16* __restrict__ qkv,
                                                    bf16* __restrict__ y,
                                                    const int* __restrict__ winp) {
    // bid remap: group 0 (bids 0..255) -> qt 15..8 (long), group 1 -> qt 0..7 (short)
    const int bid = blockIdx.x;
    const int group = bid >> 8, idx = bid & 255;
    const int bh = idx >> 3, jj = idx & 7;
    const int qt = group ? jj : (15 - jj);
    const int h = bh & 15, b = bh >> 4;
    const int t0 = qt * 128;
    const int kvh = h >> 2;
    const int tid = threadIdx.x;
    const int lane = tid & 63;
    const int w = tid >> 6;
    const int window = winp[0];

    __shared__ __align__(16) bf16 Ks[2][64 * 128];  // 32 KB, XOR-swizzled storage
    __shared__ __align__(16) bf16 Vt[128 * 64];     // 16 KB, [d][slot], XOR-swizzled
    __shared__ __align__(16) bf16 Ps[4][32 * 64];   // 16 KB, [w][row][slot], XOR-swizzled

    const int fr = lane & 15;
    const int kq = (lane >> 4) * 8;
    const int hi = lane >> 4;

    // Q fragments: 2 m-frags x 4 k-chunks
    short8 qf[2][4];
#pragma unroll
    for (int mi = 0; mi < 2; ++mi) {
        const bf16* qp = qkv + ((size_t)(b * TT) + t0 + w * 32 + mi * 16 + fr) * NQKV + h * HDq;
#pragma unroll
        for (int c = 0; c < 4; ++c)
            qf[mi][c] = *reinterpret_cast<const short8*>(&qp[c * 32 + kq]);
    }

    f32x4 acc[2][8];
#pragma unroll
    for (int mi = 0; mi < 2; ++mi)
#pragma unroll
        for (int n = 0; n < 8; ++n) acc[mi][n] = f32x4{0.f, 0.f, 0.f, 0.f};
    float m2[2][4], lrow[2][4];   // lrow = per-lane PARTIAL sum (deferred reduce)
#pragma unroll
    for (int mi = 0; mi < 2; ++mi)
#pragma unroll
        for (int j = 0; j < 4; ++j) { m2[mi][j] = -1e30f; lrow[mi][j] = 0.f; }

    int s_lo = t0 - window; if (s_lo < 0) s_lo = 0; s_lo &= ~63;
    const int s_end = t0 + 128;

    const bf16* Kg = qkv + (size_t)b * TT * NQKV + 2048 + kvh * HDq;
    const bf16* Vg = Kg + 512;

    const int str = tid >> 4;            // K staging: row within 16-row group
    const int sti = tid & 15;            // K staging: 16B chunk index
    const int vf  = tid & 15;            // V staging: fr-slot group (keys 16n+vf)
    const int vdc = (tid >> 4) * 8;      // V staging: 8 d cols
    const float scl2 = 0.08838834764831845f * 1.4426950408889634f;  // 1/sqrt(128)*log2(e)
    const float THR2 = 11.54f;           // defer-max threshold (8 nats in base-2)

    short8 vr[4];

    // ---- prime: stage tile s_lo ----
#pragma unroll
    for (int p = 0; p < 4; ++p) {
        int row = p * 16 + str;
        int c16 = sti ^ (row & 7);
        gll16(&Kg[(size_t)(s_lo + row) * NQKV + c16 * 8], (char*)Ks + p * 4096 + tid * 16);
    }
#pragma unroll
    for (int i = 0; i < 4; ++i)
        vr[i] = *reinterpret_cast<const short8*>(&Vg[(size_t)(s_lo + 16 * i + vf) * NQKV + vdc]);
#pragma unroll
    for (int j = 0; j < 8; ++j) {
        short4v col;
        col[0] = vr[0][j]; col[1] = vr[1][j]; col[2] = vr[2][j]; col[3] = vr[3][j];
        *reinterpret_cast<short4v*>((char*)Vt + (vdc + j) * 128 + ((8 * vf) ^ (j << 4))) = col;
    }
    __syncthreads();   // drains gll16 (vmcnt) + ds_writes (lgkm)

    int cur = 0;
    for (int sk = s_lo; sk < s_end; sk += 64) {
        const bool hn = (sk + 64 < s_end);
        // ---- prefetch next tile: K -> Ks[cur^1] (async LDS), V -> regs ----
        if (hn) {
#pragma unroll
            for (int p = 0; p < 4; ++p) {
                int row = p * 16 + str;
                int c16 = sti ^ (row & 7);
                gll16(&Kg[(size_t)(sk + 64 + row) * NQKV + c16 * 8],
                      (char*)Ks + (cur ^ 1) * 16384 + p * 4096 + tid * 16);
            }
#pragma unroll
            for (int i = 0; i < 4; ++i)
                vr[i] = *reinterpret_cast<const short8*>(&Vg[(size_t)(sk + 64 + 16 * i + vf) * NQKV + vdc]);
        }

        // ---- QK^T on Ks[cur] ----
        f32x4 S[2][4];
#pragma unroll
        for (int mi = 0; mi < 2; ++mi)
#pragma unroll
            for (int n = 0; n < 4; ++n) S[mi][n] = f32x4{0.f, 0.f, 0.f, 0.f};
        __builtin_amdgcn_s_setprio(1);
#pragma unroll
        for (int n = 0; n < 4; ++n) {
            int rb = n * 16 + fr;
#pragma unroll
            for (int c = 0; c < 4; ++c) {
                int colb = c * 64 + kq * 2;
                short8 kf = *reinterpret_cast<const short8*>(
                    (const char*)Ks + cur * 16384 + rb * 256 + (colb ^ ((rb & 7) << 4)));
                S[0][n] = MFMA16(qf[0][c], kf, S[0][n]);
                S[1][n] = MFMA16(qf[1][c], kf, S[1][n]);
            }
        }
        __builtin_amdgcn_s_setprio(0);

        // ---- online softmax (deferred l-sum, slot-packed P write) ----
        const int rw0 = t0 + w * 32;
        const bool interior = (sk + 63 <= rw0) && (rw0 + 31 - sk <= window);
#pragma unroll
        for (int mi = 0; mi < 2; ++mi) {
#pragma unroll
            for (int j = 0; j < 4; ++j) {
                const int rl = hi * 4 + j;
                float s0, s1, s2, s3;
                if (interior) {
                    s0 = S[mi][0][j] * scl2; s1 = S[mi][1][j] * scl2;
                    s2 = S[mi][2][j] * scl2; s3 = S[mi][3][j] * scl2;
                } else {
                    const int r = rw0 + mi * 16 + rl;
                    int c0 = sk + fr, c1 = c0 + 16, c2 = c0 + 32, c3 = c0 + 48;
                    s0 = (c0 <= r && r - c0 <= window) ? S[mi][0][j] * scl2 : -1e30f;
                    s1 = (c1 <= r && r - c1 <= window) ? S[mi][1][j] * scl2 : -1e30f;
                    s2 = (c2 <= r && r - c2 <= window) ? S[mi][2][j] * scl2 : -1e30f;
                    s3 = (c3 <= r && r - c3 <= window) ? S[mi][3][j] * scl2 : -1e30f;
                }
                float pm = fmaxf(fmaxf(s0, s1), fmaxf(s2, s3));
                if (!__all(pm <= m2[mi][j] + THR2)) {       // rare: rescale
                    float pr = pm;
#pragma unroll
                    for (int mm = 1; mm < 16; mm <<= 1) pr = fmaxf(pr, __shfl_xor(pr, mm));
                    float nm = fmaxf(m2[mi][j], pr);
                    float corr = exp2f(m2[mi][j] - nm);
                    m2[mi][j] = nm;
                    lrow[mi][j] *= corr;
#pragma unroll
                    for (int n = 0; n < 8; ++n) acc[mi][n][j] *= corr;
                }
                float p0 = exp2f(s0 - m2[mi][j]);
                float p1 = exp2f(s1 - m2[mi][j]);
                float p2 = exp2f(s2 - m2[mi][j]);
                float p3 = exp2f(s3 - m2[mi][j]);
                if (!interior) {   // kill exp2(-inf - -inf)=1 artifacts on fully-masked rows
                    p0 = (s0 > -1e29f) ? p0 : 0.f;
                    p1 = (s1 > -1e29f) ? p1 : 0.f;
                    p2 = (s2 > -1e29f) ? p2 : 0.f;
                    p3 = (s3 > -1e29f) ? p3 : 0.f;
                }
                lrow[mi][j] += (p0 + p1) + (p2 + p3);    // per-lane partial, no shuffle
                short4v pk;                               // slots 4*fr + n  (key = 16n+fr)
                pk[0] = (short)__bfloat16_as_ushort(__float2bfloat16(p0));
                pk[1] = (short)__bfloat16_as_ushort(__float2bfloat16(p1));
                pk[2] = (short)__bfloat16_as_ushort(__float2bfloat16(p2));
                pk[3] = (short)__bfloat16_as_ushort(__float2bfloat16(p3));
                const int prow = mi * 16 + rl;
                *reinterpret_cast<short4v*>(
                    (char*)Ps + w * 4096 + prow * 128 + ((8 * fr) ^ ((prow & 7) << 4))) = pk;
            }
        }

        // ---- PV: O[2 mi][8 d-frags] += P[32x64] * V[64x128]  (slot space) ----
        __builtin_amdgcn_s_setprio(1);
#pragma unroll
        for (int c2 = 0; c2 < 2; ++c2) {
            short8 pa0 = *reinterpret_cast<const short8*>(
                (char*)Ps + w * 4096 + fr * 128 + ((c2 * 64 + hi * 16) ^ ((fr & 7) << 4)));
            short8 pa1 = *reinterpret_cast<const short8*>(
                (char*)Ps + w * 4096 + (16 + fr) * 128 + ((c2 * 64 + hi * 16) ^ ((fr & 7) << 4)));
#pragma unroll
            for (int n = 0; n < 8; ++n) {
                short8 vb = *reinterpret_cast<const short8*>(
                    (char*)Vt + (n * 16 + fr) * 128 + ((c2 * 64 + hi * 16) ^ ((fr & 7) << 4)));
                acc[0][n] = MFMA16(pa0, vb, acc[0][n]);
                acc[1][n] = MFMA16(pa1, vb, acc[1][n]);
            }
        }
        __builtin_amdgcn_s_setprio(0);

        __syncthreads();               // all waves done reading Vt (+ Ks[cur])
        if (hn) {
#pragma unroll
            for (int j = 0; j < 8; ++j) {   // vr arrived (vmcnt dep); write next Vt
                short4v col;
                col[0] = vr[0][j]; col[1] = vr[1][j]; col[2] = vr[2][j]; col[3] = vr[3][j];
                *reinterpret_cast<short4v*>((char*)Vt + (vdc + j) * 128 + ((8 * vf) ^ (j << 4))) = col;
            }
        }
        __syncthreads();               // Vt + Ks[cur^1] ready (compiler drains vmcnt/lgkm)
        cur ^= 1;
    }

    // ---- epilogue: reduce deferred l-sum (16-lane group), normalize + write ----
#pragma unroll
    for (int mi = 0; mi < 2; ++mi)
#pragma unroll
        for (int j = 0; j < 4; ++j) {
            float l = lrow[mi][j];
#pragma unroll
            for (int mm = 1; mm < 16; mm <<= 1) l += __shfl_xor(l, mm);
            const int r = t0 + w * 32 + mi * 16 + hi * 4 + j;
            float inv = 1.f / l;
            bf16* yr = y + ((size_t)(b * TT) + r) * CC + h * HDq;
#pragma unroll
            for (int n = 0; n < 8; ++n)
                yr[n * 16 + fr] = __float2bfloat16(acc[mi][n][j] * inv);
        }
}

extern "C" void kernel_launch(void* const* d_in, const int* in_sizes, int n_in,
                              void* d_out, int out_size, void* d_ws, size_t ws_size,
                              hipStream_t stream) {
    const float* x     = (const float*)d_in[0];
    const float* ve    = (const float*)d_in[1];
    const float* cosb  = (const float*)d_in[2];
    const float* sinb  = (const float*)d_in[3];
    const float* Wq    = (const float*)d_in[4];
    const float* Wk    = (const float*)d_in[5];
    const float* Wv    = (const float*)d_in[6];
    const float* Wproj = (const float*)d_in[7];
    const float* Wgate = (const float*)d_in[8];
    const int*   winp  = (const int*)d_in[9];

    bf16* xb     = (bf16*)d_ws;
    bf16* wqkvb  = xb + (size_t)ROWS * CC;
    bf16* wprojb = wqkvb + (size_t)NQKV * CC;
    bf16* qkvb   = wprojb + (size_t)CC * CC;
    bf16* yb     = xb;   // alias: xb dead after qkv GEMM

    // 1) fused casts (Wq/Wk rows chunk-swapped for the RoPE-local epilogue)
    cast_all<<<18432, 256, 0, stream>>>(x, Wq, Wk, Wv, Wproj, xb);

    // 2) qkv = x @ [Wq;Wk;Wv]^T with fused gate/ve + RoPE + RMSNorm epilogue
    gemm_qkv<<<dim3(ROWS / 128, NQKV / 128), 256, 0, stream>>>(xb, wqkvb, qkvb,
                                                               x, ve, cosb, sinb, Wgate);

    // 3) MFMA flash attention -> yb
    attn_mfma<<<BB * NHq * (TT / 128), 256, 0, stream>>>(qkvb, yb, winp);

    // 4) out = y @ Wproj^T (fp32 out)
    gemm_bt<1><<<dim3(ROWS / 128, CC / 128), 256, 0, stream>>>(yb, wprojb, d_out, ROWS, CC, CC);
}

// Round 8
// 234.333 us; speedup vs baseline: 1.0333x; 1.0333x over previous
//
#include <hip/hip_runtime.h>
#include <hip/hip_bf16.h>

// Problem constants (reference: B=2, T=2048, C=2048, NH=16, NKV=4, HD=128, GATE_CH=12)
#define BB   2
#define TT   2048
#define CC   2048
#define NHq  16
#define NKVq 4
#define HDq  128
#define ROWS (BB*TT)          // 4096
#define NQKV (NHq*HDq + 2*NKVq*HDq)  // 3072

using bf16 = __hip_bfloat16;
using short8  = __attribute__((ext_vector_type(8))) short;
using short4v = __attribute__((ext_vector_type(4))) short;
using f32x4   = __attribute__((ext_vector_type(4))) float;

#define MFMA16(a,b,c) __builtin_amdgcn_mfma_f32_16x16x32_bf16((a),(b),(c),0,0,0)

// async global->LDS, 16B per lane. LDS dest must be wave-uniform-base + lane*16.
__device__ __forceinline__ void gll16(const bf16* g, void* l) {
    __builtin_amdgcn_global_load_lds((const __attribute__((address_space(1))) void*)g,
                                     (__attribute__((address_space(3))) void*)l,
                                     16, 0, 0);
}

// ---------------- fused cast: all fp32 inputs -> contiguous bf16 ws regions ----------------
// dst layout: [xb 8388608 | wq 4194304 | wk 1048576 | wv 1048576 | wproj 4194304]
// Wq/Wk rows are chunk-swapped (32-chunks 1<->2 within each 128-row head) so the
// fused RoPE epilogue in gemm_qkv has both rotation partners register-local.
__global__ void cast_all(const float* __restrict__ x,  const float* __restrict__ wq,
                         const float* __restrict__ wk, const float* __restrict__ wv,
                         const float* __restrict__ wp, bf16* __restrict__ dst) {
    long e = ((long)blockIdx.x * 256 + threadIdx.x) * 4;
    const float* src; long off; long dsto = e; int permute = 0; long rbase = 0;
    if (e < 8388608L)       { src = x;  off = e; }
    else if (e < 12582912L) { src = wq; off = e - 8388608L;  permute = 1; rbase = 8388608L; }
    else if (e < 13631488L) { src = wk; off = e - 12582912L; permute = 1; rbase = 12582912L; }
    else if (e < 14680064L) { src = wv; off = e - 13631488L; }
    else                    { src = wp; off = e - 14680064L; }
    if (permute) {
        long row = off >> 11, col = off & 2047;
        int hl = (int)(row & 127), c = hl >> 5;
        int hl2 = (c == 1) ? hl + 32 : (c == 2) ? hl - 32 : hl;
        dsto = rbase + ((row & ~127L) | hl2) * 2048 + col;
    }
    float4 v = *reinterpret_cast<const float4*>(src + off);
    ushort4 o;
    o.x = __bfloat16_as_ushort(__float2bfloat16(v.x));
    o.y = __bfloat16_as_ushort(__float2bfloat16(v.y));
    o.z = __bfloat16_as_ushort(__float2bfloat16(v.z));
    o.w = __bfloat16_as_ushort(__float2bfloat16(v.w));
    *reinterpret_cast<ushort4*>(dst + dsto) = o;
}

// ---------------- prep: packed cos/sin table ----------------
// cs[t][i] = {cos(t,d0), sin(t,d0), cos(t,d1), sin(t,d1)}, i = wc*16+cc,
// d0 = (i>>4)*32 + (i&15), d1 = d0 + 16. One coalesced float4 per epilogue (m,j).
__global__ void prep_cs(const float* __restrict__ cosb, const float* __restrict__ sinb,
                        float4* __restrict__ cs) {
    int id = blockIdx.x * 256 + threadIdx.x;       // t*32 + i, 65536 total
    int t = id >> 5, i = id & 31;
    int d0 = (i >> 4) * 32 + (i & 15);
    int d1 = d0 + 16;
    cs[id] = float4{cosb[t * 64 + d0], sinb[t * 64 + d0],
                    cosb[t * 64 + d1], sinb[t * 64 + d1]};
}

// ---------------- bf16 MFMA GEMM (m97, natural block order), used for out-proj ----------------
template<int OUT_F32>
__global__ __launch_bounds__(256) void gemm_bt(const bf16* __restrict__ A,
                                               const bf16* __restrict__ B,
                                               void* __restrict__ Cp,
                                               int M, int N, int K) {
    const int bm = blockIdx.x * 128;
    const int bn = blockIdx.y * 128;
    const int tid = threadIdx.x;
    const int lane = tid & 63;
    const int w = tid >> 6;
    const int wr = w >> 1, wc = w & 1;   // 2x2 waves of 64x64

    __shared__ __align__(16) bf16 As[128 * 32];
    __shared__ __align__(16) bf16 Bs[128 * 32];

    f32x4 acc[4][4];
#pragma unroll
    for (int i = 0; i < 4; ++i)
#pragma unroll
        for (int j = 0; j < 4; ++j) acc[i][j] = f32x4{0.f, 0.f, 0.f, 0.f};

    const int srow = tid >> 2;
    const int scol = (tid & 3) * 8;

    for (int k0 = 0; k0 < K; k0 += 32) {
        __syncthreads();
#pragma unroll
        for (int p = 0; p < 2; ++p) {
            gll16(&A[(size_t)(bm + p * 64 + srow) * K + k0 + scol], (char*)As + p * 4096 + tid * 16);
            gll16(&B[(size_t)(bn + p * 64 + srow) * K + k0 + scol], (char*)Bs + p * 4096 + tid * 16);
        }
        __syncthreads();

        const int fr = lane & 15;
        const int kq = (lane >> 4) * 8;
        short8 af[4], bfr[4];
#pragma unroll
        for (int m = 0; m < 4; ++m)
            af[m] = *reinterpret_cast<const short8*>(&As[(wr * 64 + m * 16 + fr) * 32 + kq]);
#pragma unroll
        for (int n = 0; n < 4; ++n)
            bfr[n] = *reinterpret_cast<const short8*>(&Bs[(wc * 64 + n * 16 + fr) * 32 + kq]);
#pragma unroll
        for (int m = 0; m < 4; ++m)
#pragma unroll
            for (int n = 0; n < 4; ++n)
                acc[m][n] = MFMA16(af[m], bfr[n], acc[m][n]);
    }

    const int cr = (lane >> 4) * 4;
    const int cc = lane & 15;
#pragma unroll
    for (int m = 0; m < 4; ++m)
#pragma unroll
        for (int n = 0; n < 4; ++n) {
            int row = bm + wr * 64 + m * 16 + cr;
            int col = bn + wc * 64 + n * 16 + cc;
#pragma unroll
            for (int j = 0; j < 4; ++j) {
                float v = acc[m][n][j];
                if (OUT_F32) ((float*)Cp)[(size_t)(row + j) * N + col] = v;
                else         ((bf16*)Cp)[(size_t)(row + j) * N + col] = __float2bfloat16(v);
            }
        }
}

// ---------------- qkv GEMM, 64x64 wave-tiles, fused postproc (latency-hoisted) ----------------
// B rows chunk-swapped at cast: wave (wr,wc) holds RoPE pairs register-locally:
// d = wc*32 + p*16 + cc (p=0,1), x1=acc[m][p], x2=acc[m][p+2]. RMSNorm partials
// exchanged between wc-paired waves via 1KB LDS. cos/sin via packed float4 table.
// v blocks: gate 12-dot computed into LDS BEFORE the K-loop (latency hidden).
__global__ __launch_bounds__(256) void gemm_qkv(const bf16* __restrict__ A,
                                                const bf16* __restrict__ B,
                                                bf16* __restrict__ qkv,
                                                const float* __restrict__ x,
                                                const float* __restrict__ ve,
                                                const float4* __restrict__ csTab,
                                                const float* __restrict__ Wgate) {
    const int K = CC;
    const int bm = blockIdx.x * 128;
    const int bn = blockIdx.y * 128;
    const int tid = threadIdx.x;
    const int lane = tid & 63;
    const int w = tid >> 6;
    const int wr = w >> 1, wc = w & 1;

    __shared__ __align__(16) bf16 As[128 * 32];
    __shared__ __align__(16) bf16 Bs[128 * 32];
    __shared__ float exch[2][2][64];   // [wc][wr][local row] RMS partials
    __shared__ float gate_s[128];      // v-blocks: per-row gate

    // ---- v-blocks: gate 12-dot before the loop (hides under first staging) ----
    if (bn >= 2560 && tid < 128) {
        const int kvh = (bn - 2560) >> 7;
        float g = 0.f;
#pragma unroll
        for (int c = 0; c < 12; ++c) g += x[(size_t)(bm + tid) * CC + c] * Wgate[kvh * 12 + c];
        gate_s[tid] = 3.0f / (1.0f + __expf(-g));
    }

    f32x4 acc[4][4];
#pragma unroll
    for (int i = 0; i < 4; ++i)
#pragma unroll
        for (int j = 0; j < 4; ++j) acc[i][j] = f32x4{0.f, 0.f, 0.f, 0.f};

    const int srow = tid >> 2;
    const int scol = (tid & 3) * 8;

    for (int k0 = 0; k0 < K; k0 += 32) {
        __syncthreads();
#pragma unroll
        for (int p = 0; p < 2; ++p) {
            gll16(&A[(size_t)(bm + p * 64 + srow) * K + k0 + scol], (char*)As + p * 4096 + tid * 16);
            gll16(&B[(size_t)(bn + p * 64 + srow) * K + k0 + scol], (char*)Bs + p * 4096 + tid * 16);
        }
        __syncthreads();

        const int fr = lane & 15;
        const int kq = (lane >> 4) * 8;
        short8 af[4], bfr[4];
#pragma unroll
        for (int m = 0; m < 4; ++m)
            af[m] = *reinterpret_cast<const short8*>(&As[(wr * 64 + m * 16 + fr) * 32 + kq]);
#pragma unroll
        for (int n = 0; n < 4; ++n)
            bfr[n] = *reinterpret_cast<const short8*>(&Bs[(wc * 64 + n * 16 + fr) * 32 + kq]);
#pragma unroll
        for (int m = 0; m < 4; ++m)
#pragma unroll
            for (int n = 0; n < 4; ++n)
                acc[m][n] = MFMA16(af[m], bfr[n], acc[m][n]);
    }

    const int cc_ = lane & 15;
    const int hi  = lane >> 4;

    if (bn < 2560) {
        // ---- RoPE + RMSNorm + *1.2 (packed float4 cos/sin loads) ----
        const int ci = wc * 16 + cc_;
#pragma unroll
        for (int m = 0; m < 4; ++m)
#pragma unroll
            for (int j = 0; j < 4; ++j) {
                const int row = bm + wr * 64 + m * 16 + hi * 4 + j;
                const int t = row & (TT - 1);
                float4 cs = csTab[t * 32 + ci];
                float ss = 0.f;
                {
                    float x1 = acc[m][0][j], x2 = acc[m][2][j];
                    float r1 =  x1 * cs.x + x2 * cs.y;
                    float r2 = -x1 * cs.y + x2 * cs.x;
                    ss += r1 * r1 + r2 * r2;
                    acc[m][0][j] = r1; acc[m][2][j] = r2;
                }
                {
                    float x1 = acc[m][1][j], x2 = acc[m][3][j];
                    float r1 =  x1 * cs.z + x2 * cs.w;
                    float r2 = -x1 * cs.w + x2 * cs.z;
                    ss += r1 * r1 + r2 * r2;
                    acc[m][1][j] = r1; acc[m][3][j] = r2;
                }
#pragma unroll
                for (int mm = 1; mm < 16; mm <<= 1) ss += __shfl_xor(ss, mm);
                if (cc_ == 0) exch[wc][wr][m * 16 + hi * 4 + j] = ss;
            }
        __syncthreads();
#pragma unroll
        for (int m = 0; m < 4; ++m)
#pragma unroll
            for (int j = 0; j < 4; ++j) {
                const int row = bm + wr * 64 + m * 16 + hi * 4 + j;
                const int lr = m * 16 + hi * 4 + j;
                float sst = exch[0][wr][lr] + exch[1][wr][lr];
                float sc = rsqrtf(sst * (1.0f / 128.0f) + 1e-6f) * 1.2f;
                bf16* o = qkv + (size_t)row * NQKV + bn;
#pragma unroll
                for (int p = 0; p < 2; ++p) {
                    const int d = wc * 32 + p * 16 + cc_;
                    o[d]      = __float2bfloat16(acc[m][p][j] * sc);
                    o[d + 64] = __float2bfloat16(acc[m][p + 2][j] * sc);
                }
            }
    } else {
        // ---- v: gate + ve add (gate from LDS) ----
        const int kvh = (bn - 2560) >> 7;
#pragma unroll
        for (int m = 0; m < 4; ++m)
#pragma unroll
            for (int j = 0; j < 4; ++j) {
                const int lr = wr * 64 + m * 16 + hi * 4 + j;
                const int row = bm + lr;
                const float g = gate_s[lr];
                bf16* o = qkv + (size_t)row * NQKV + bn + wc * 64;
                const float* vep = ve + (size_t)row * 512 + kvh * 128 + wc * 64;
#pragma unroll
                for (int n = 0; n < 4; ++n) {
                    const int d = n * 16 + cc_;
                    o[d] = __float2bfloat16(acc[m][n][j] + g * vep[d]);
                }
            }
    }
}

// ---------------- MFMA flash attention v5 (unchanged from R6) ----------------
__global__ __launch_bounds__(256, 2) void attn_mfma(const bf16* __restrict__ qkv,
                                                    bf16* __restrict__ y,
                                                    const int* __restrict__ winp) {
    const int bid = blockIdx.x;
    const int group = bid >> 8, idx = bid & 255;
    const int bh = idx >> 3, jj = idx & 7;
    const int qt = group ? jj : (15 - jj);
    const int h = bh & 15, b = bh >> 4;
    const int t0 = qt * 128;
    const int kvh = h >> 2;
    const int tid = threadIdx.x;
    const int lane = tid & 63;
    const int w = tid >> 6;
    const int window = winp[0];

    __shared__ __align__(16) bf16 Ks[2][64 * 128];  // 32 KB, XOR-swizzled storage
    __shared__ __align__(16) bf16 Vt[128 * 64];     // 16 KB, [d][slot], XOR-swizzled
    __shared__ __align__(16) bf16 Ps[4][32 * 64];   // 16 KB, [w][row][slot], XOR-swizzled

    const int fr = lane & 15;
    const int kq = (lane >> 4) * 8;
    const int hi = lane >> 4;

    short8 qf[2][4];
#pragma unroll
    for (int mi = 0; mi < 2; ++mi) {
        const bf16* qp = qkv + ((size_t)(b * TT) + t0 + w * 32 + mi * 16 + fr) * NQKV + h * HDq;
#pragma unroll
        for (int c = 0; c < 4; ++c)
            qf[mi][c] = *reinterpret_cast<const short8*>(&qp[c * 32 + kq]);
    }

    f32x4 acc[2][8];
#pragma unroll
    for (int mi = 0; mi < 2; ++mi)
#pragma unroll
        for (int n = 0; n < 8; ++n) acc[mi][n] = f32x4{0.f, 0.f, 0.f, 0.f};
    float m2[2][4], lrow[2][4];
#pragma unroll
    for (int mi = 0; mi < 2; ++mi)
#pragma unroll
        for (int j = 0; j < 4; ++j) { m2[mi][j] = -1e30f; lrow[mi][j] = 0.f; }

    int s_lo = t0 - window; if (s_lo < 0) s_lo = 0; s_lo &= ~63;
    const int s_end = t0 + 128;

    const bf16* Kg = qkv + (size_t)b * TT * NQKV + 2048 + kvh * HDq;
    const bf16* Vg = Kg + 512;

    const int str = tid >> 4;
    const int sti = tid & 15;
    const int vf  = tid & 15;
    const int vdc = (tid >> 4) * 8;
    const float scl2 = 0.08838834764831845f * 1.4426950408889634f;
    const float THR2 = 11.54f;

    short8 vr[4];

#pragma unroll
    for (int p = 0; p < 4; ++p) {
        int row = p * 16 + str;
        int c16 = sti ^ (row & 7);
        gll16(&Kg[(size_t)(s_lo + row) * NQKV + c16 * 8], (char*)Ks + p * 4096 + tid * 16);
    }
#pragma unroll
    for (int i = 0; i < 4; ++i)
        vr[i] = *reinterpret_cast<const short8*>(&Vg[(size_t)(s_lo + 16 * i + vf) * NQKV + vdc]);
#pragma unroll
    for (int j = 0; j < 8; ++j) {
        short4v col;
        col[0] = vr[0][j]; col[1] = vr[1][j]; col[2] = vr[2][j]; col[3] = vr[3][j];
        *reinterpret_cast<short4v*>((char*)Vt + (vdc + j) * 128 + ((8 * vf) ^ (j << 4))) = col;
    }
    __syncthreads();

    int cur = 0;
    for (int sk = s_lo; sk < s_end; sk += 64) {
        const bool hn = (sk + 64 < s_end);
        if (hn) {
#pragma unroll
            for (int p = 0; p < 4; ++p) {
                int row = p * 16 + str;
                int c16 = sti ^ (row & 7);
                gll16(&Kg[(size_t)(sk + 64 + row) * NQKV + c16 * 8],
                      (char*)Ks + (cur ^ 1) * 16384 + p * 4096 + tid * 16);
            }
#pragma unroll
            for (int i = 0; i < 4; ++i)
                vr[i] = *reinterpret_cast<const short8*>(&Vg[(size_t)(sk + 64 + 16 * i + vf) * NQKV + vdc]);
        }

        f32x4 S[2][4];
#pragma unroll
        for (int mi = 0; mi < 2; ++mi)
#pragma unroll
            for (int n = 0; n < 4; ++n) S[mi][n] = f32x4{0.f, 0.f, 0.f, 0.f};
        __builtin_amdgcn_s_setprio(1);
#pragma unroll
        for (int n = 0; n < 4; ++n) {
            int rb = n * 16 + fr;
#pragma unroll
            for (int c = 0; c < 4; ++c) {
                int colb = c * 64 + kq * 2;
                short8 kf = *reinterpret_cast<const short8*>(
                    (const char*)Ks + cur * 16384 + rb * 256 + (colb ^ ((rb & 7) << 4)));
                S[0][n] = MFMA16(qf[0][c], kf, S[0][n]);
                S[1][n] = MFMA16(qf[1][c], kf, S[1][n]);
            }
        }
        __builtin_amdgcn_s_setprio(0);

        const int rw0 = t0 + w * 32;
        const bool interior = (sk + 63 <= rw0) && (rw0 + 31 - sk <= window);
#pragma unroll
        for (int mi = 0; mi < 2; ++mi) {
#pragma unroll
            for (int j = 0; j < 4; ++j) {
                const int rl = hi * 4 + j;
                float s0, s1, s2, s3;
                if (interior) {
                    s0 = S[mi][0][j] * scl2; s1 = S[mi][1][j] * scl2;
                    s2 = S[mi][2][j] * scl2; s3 = S[mi][3][j] * scl2;
                } else {
                    const int r = rw0 + mi * 16 + rl;
                    int c0 = sk + fr, c1 = c0 + 16, c2 = c0 + 32, c3 = c0 + 48;
                    s0 = (c0 <= r && r - c0 <= window) ? S[mi][0][j] * scl2 : -1e30f;
                    s1 = (c1 <= r && r - c1 <= window) ? S[mi][1][j] * scl2 : -1e30f;
                    s2 = (c2 <= r && r - c2 <= window) ? S[mi][2][j] * scl2 : -1e30f;
                    s3 = (c3 <= r && r - c3 <= window) ? S[mi][3][j] * scl2 : -1e30f;
                }
                float pm = fmaxf(fmaxf(s0, s1), fmaxf(s2, s3));
                if (!__all(pm <= m2[mi][j] + THR2)) {
                    float pr = pm;
#pragma unroll
                    for (int mm = 1; mm < 16; mm <<= 1) pr = fmaxf(pr, __shfl_xor(pr, mm));
                    float nm = fmaxf(m2[mi][j], pr);
                    float corr = exp2f(m2[mi][j] - nm);
                    m2[mi][j] = nm;
                    lrow[mi][j] *= corr;
#pragma unroll
                    for (int n = 0; n < 8; ++n) acc[mi][n][j] *= corr;
                }
                float p0 = exp2f(s0 - m2[mi][j]);
                float p1 = exp2f(s1 - m2[mi][j]);
                float p2 = exp2f(s2 - m2[mi][j]);
                float p3 = exp2f(s3 - m2[mi][j]);
                if (!interior) {
                    p0 = (s0 > -1e29f) ? p0 : 0.f;
                    p1 = (s1 > -1e29f) ? p1 : 0.f;
                    p2 = (s2 > -1e29f) ? p2 : 0.f;
                    p3 = (s3 > -1e29f) ? p3 : 0.f;
                }
                lrow[mi][j] += (p0 + p1) + (p2 + p3);
                short4v pk;
                pk[0] = (short)__bfloat16_as_ushort(__float2bfloat16(p0));
                pk[1] = (short)__bfloat16_as_ushort(__float2bfloat16(p1));
                pk[2] = (short)__bfloat16_as_ushort(__float2bfloat16(p2));
                pk[3] = (short)__bfloat16_as_ushort(__float2bfloat16(p3));
                const int prow = mi * 16 + rl;
                *reinterpret_cast<short4v*>(
                    (char*)Ps + w * 4096 + prow * 128 + ((8 * fr) ^ ((prow & 7) << 4))) = pk;
            }
        }

        __builtin_amdgcn_s_setprio(1);
#pragma unroll
        for (int c2 = 0; c2 < 2; ++c2) {
            short8 pa0 = *reinterpret_cast<const short8*>(
                (char*)Ps + w * 4096 + fr * 128 + ((c2 * 64 + hi * 16) ^ ((fr & 7) << 4)));
            short8 pa1 = *reinterpret_cast<const short8*>(
                (char*)Ps + w * 4096 + (16 + fr) * 128 + ((c2 * 64 + hi * 16) ^ ((fr & 7) << 4)));
#pragma unroll
            for (int n = 0; n < 8; ++n) {
                short8 vb = *reinterpret_cast<const short8*>(
                    (char*)Vt + (n * 16 + fr) * 128 + ((c2 * 64 + hi * 16) ^ ((fr & 7) << 4)));
                acc[0][n] = MFMA16(pa0, vb, acc[0][n]);
                acc[1][n] = MFMA16(pa1, vb, acc[1][n]);
            }
        }
        __builtin_amdgcn_s_setprio(0);

        __syncthreads();
        if (hn) {
#pragma unroll
            for (int j = 0; j < 8; ++j) {
                short4v col;
                col[0] = vr[0][j]; col[1] = vr[1][j]; col[2] = vr[2][j]; col[3] = vr[3][j];
                *reinterpret_cast<short4v*>((char*)Vt + (vdc + j) * 128 + ((8 * vf) ^ (j << 4))) = col;
            }
        }
        __syncthreads();
        cur ^= 1;
    }

#pragma unroll
    for (int mi = 0; mi < 2; ++mi)
#pragma unroll
        for (int j = 0; j < 4; ++j) {
            float l = lrow[mi][j];
#pragma unroll
            for (int mm = 1; mm < 16; mm <<= 1) l += __shfl_xor(l, mm);
            const int r = t0 + w * 32 + mi * 16 + hi * 4 + j;
            float inv = 1.f / l;
            bf16* yr = y + ((size_t)(b * TT) + r) * CC + h * HDq;
#pragma unroll
            for (int n = 0; n < 8; ++n)
                yr[n * 16 + fr] = __float2bfloat16(acc[mi][n][j] * inv);
        }
}

extern "C" void kernel_launch(void* const* d_in, const int* in_sizes, int n_in,
                              void* d_out, int out_size, void* d_ws, size_t ws_size,
                              hipStream_t stream) {
    const float* x     = (const float*)d_in[0];
    const float* ve    = (const float*)d_in[1];
    const float* cosb  = (const float*)d_in[2];
    const float* sinb  = (const float*)d_in[3];
    const float* Wq    = (const float*)d_in[4];
    const float* Wk    = (const float*)d_in[5];
    const float* Wv    = (const float*)d_in[6];
    const float* Wproj = (const float*)d_in[7];
    const float* Wgate = (const float*)d_in[8];
    const int*   winp  = (const int*)d_in[9];

    bf16* xb     = (bf16*)d_ws;
    bf16* wqkvb  = xb + (size_t)ROWS * CC;
    bf16* wprojb = wqkvb + (size_t)NQKV * CC;
    bf16* qkvb   = wprojb + (size_t)CC * CC;
    float4* csT  = (float4*)(qkvb + (size_t)ROWS * NQKV);   // 1 MB packed cos/sin
    bf16* yb     = xb;   // alias: xb dead after qkv GEMM

    // 1) fused casts (Wq/Wk rows chunk-swapped for the RoPE-local epilogue)
    cast_all<<<18432, 256, 0, stream>>>(x, Wq, Wk, Wv, Wproj, xb);

    // 1b) packed cos/sin table
    prep_cs<<<256, 256, 0, stream>>>(cosb, sinb, csT);

    // 2) qkv = x @ [Wq;Wk;Wv]^T with fused gate/ve + RoPE + RMSNorm epilogue
    gemm_qkv<<<dim3(ROWS / 128, NQKV / 128), 256, 0, stream>>>(xb, wqkvb, qkvb,
                                                               x, ve, csT, Wgate);

    // 3) MFMA flash attention -> yb
    attn_mfma<<<BB * NHq * (TT / 128), 256, 0, stream>>>(qkvb, yb, winp);

    // 4) out = y @ Wproj^T (fp32 out)
    gemm_bt<1><<<dim3(ROWS / 128, CC / 128), 256, 0, stream>>>(yb, wprojb, d_out, ROWS, CC, CC);
}